// Round 3
// baseline (312.133 us; speedup 1.0000x reference)
//
#include <hip/hip_runtime.h>
#include <math.h>

// Tacotron2 location-sensitive attention, fp32.
// B=64 T=2048 E=512 H=128 DL=1024 CC=32 K=31
// out = [context (B*E=32768), weights (B*T=131072)] fp32, concatenated.
// 3 dispatches: k0 (prep), k1 (energies + chunk softmax stats),
// k3 (weights + context with last-block reduction).

#define BB 64
#define TT 2048
#define EE 512
#define HH 128
#define DLL 1024
#define CCC 32
#define KK 31

// ws layout (in floats)
#define WS_FW   0        // fw[128][32]                 -> 4096
#define WS_PL   4096     // pl[64][128]                 -> 8192
#define WS_EN   12288    // energies[64][2048]          -> 131072
#define WS_ST   143360   // stats[64][16][2] (m,s)      -> 2048
#define WS_CNT  145408   // int counters[64]            -> 64
#define WS_PART 145472   // partials[64][16][512]       -> 524288
// total 669760 floats = 2.68 MB

// ---------------------------------------------------------------------------
// k0: blocks 0..2047: one wave per (b,h) dot  pl[b][h] = lstm[b]·W_lstm[h]
//     block 2048: fw[h][k] = sum_c W_loc[h][c]*conv_w[c][k]; zero counters
// ---------------------------------------------------------------------------
__global__ __launch_bounds__(256) void k0_prep(const float* __restrict__ lstm,
                                               const float* __restrict__ Wl,
                                               const float* __restrict__ cw,
                                               const float* __restrict__ Wloc,
                                               float* __restrict__ ws) {
  const int blk = blockIdx.x;
  const int tid = threadIdx.x;
  if (blk < 2048) {
    const int wave = tid >> 6, lane = tid & 63;
    const int wg = blk * 4 + wave;      // 0..8191
    const int b = wg >> 7, h = wg & 127;
    const float4* wr = (const float4*)(Wl + (size_t)h * DLL);
    const float4* lr = (const float4*)(lstm + (size_t)b * DLL);
    float s = 0.f;
#pragma unroll
    for (int m = 0; m < 4; ++m) {
      float4 a = wr[m * 64 + lane];
      float4 c = lr[m * 64 + lane];
      s += a.x * c.x + a.y * c.y + a.z * c.z + a.w * c.w;
    }
#pragma unroll
    for (int m = 1; m < 64; m <<= 1) s += __shfl_xor(s, m, 64);
    if (lane == 0) ws[WS_PL + b * HH + h] = s;
  } else {
    if (tid < 64) ((int*)(ws + WS_CNT))[tid] = 0;  // ctx reduction counters
    __shared__ __align__(16) float wl_s[HH * CCC];  // 4096
    __shared__ __align__(16) float cw_s[CCC * KK];  // 992
#pragma unroll
    for (int m = 0; m < 4; ++m)
      ((float4*)wl_s)[tid + 256 * m] = ((const float4*)Wloc)[tid + 256 * m];
    if (tid < 248) ((float4*)cw_s)[tid] = ((const float4*)cw)[tid];
    __syncthreads();
    const int h = tid >> 1;
    const int kbase = (tid & 1) * 16;
    const int kn = (tid & 1) ? 15 : 16;
    for (int kk = 0; kk < kn; ++kk) {
      const int k = kbase + kk;
      float s = 0.f;
#pragma unroll
      for (int c = 0; c < CCC; ++c) s += wl_s[h * CCC + c] * cw_s[c * KK + k];
      ws[WS_FW + h * 32 + k] = s;
    }
    if (tid & 1) ws[WS_FW + h * 32 + 31] = 0.f;  // pad
  }
}

// ---------------------------------------------------------------------------
// k1: energies[b][t] = sum_h We[h] * tanh(pl[b][h] + pe[b][t][h] + conv_h)
//     conv_h = sum_k fw[h][k] * aw[b][t+k-15] (zero pad)
// Also: per-block online softmax stats (m_c, s_c) -> ws stats.
// t-chunk 128 per block, grid (16,64). One wave per 4 consecutive t;
// lane owns h in {2*lane, 2*lane+1}.
// ---------------------------------------------------------------------------
__global__ __launch_bounds__(256) void k1_energies(const float* __restrict__ pe,
                                                   const float* __restrict__ aw,
                                                   const float* __restrict__ We,
                                                   float* __restrict__ ws) {
  const int b = blockIdx.y;
  const int chunk = blockIdx.x;
  const int t0 = chunk * 128;
  const int tid = threadIdx.x;
  const int wave = tid >> 6, lane = tid & 63;

  __shared__ __align__(16) float aw_s[160];  // aw[t0-16 .. t0+143], zero-pad
  if (tid < 160) {
    const int tg = t0 - 16 + tid;
    aw_s[tid] = (tg >= 0 && tg < TT) ? aw[b * TT + tg] : 0.f;
  }

  const int h0 = 2 * lane;
  float fw0[32], fw1[32];
  {
    const float4* f4 = (const float4*)(ws + WS_FW);
#pragma unroll
    for (int m = 0; m < 8; ++m) {
      float4 a = f4[h0 * 8 + m];
      fw0[4 * m + 0] = a.x; fw0[4 * m + 1] = a.y;
      fw0[4 * m + 2] = a.z; fw0[4 * m + 3] = a.w;
      float4 c = f4[h0 * 8 + 8 + m];
      fw1[4 * m + 0] = c.x; fw1[4 * m + 1] = c.y;
      fw1[4 * m + 2] = c.z; fw1[4 * m + 3] = c.w;
    }
  }
  const float2 plv = ((const float2*)(ws + WS_PL + b * HH))[lane];
  const float2 wev = ((const float2*)We)[lane];
  const float2* pe2 = (const float2*)(pe + (size_t)b * TT * HH);

  __syncthreads();

  float om = -3.4e38f, os = 0.f;  // online softmax (per-wave; lanes identical)

  for (int p = 0; p < 8; ++p) {
    const int tq = wave * 32 + p * 4;  // local quad start
    float2 pv[4];
#pragma unroll
    for (int j = 0; j < 4; ++j)
      pv[j] = pe2[(size_t)(t0 + tq + j) * 64 + lane];

    float w[36];
    const float4* a4 = (const float4*)&aw_s[tq];
#pragma unroll
    for (int m = 0; m < 9; ++m) {
      float4 v = a4[m];
      w[4 * m + 0] = v.x; w[4 * m + 1] = v.y;
      w[4 * m + 2] = v.z; w[4 * m + 3] = v.w;
    }

    float a0[4], a1[4];
#pragma unroll
    for (int j = 0; j < 4; ++j) {
      a0[j] = plv.x + pv[j].x;
      a1[j] = plv.y + pv[j].y;
    }
#pragma unroll
    for (int k = 0; k < 31; ++k) {
      const float f0 = fw0[k], f1 = fw1[k];
#pragma unroll
      for (int j = 0; j < 4; ++j) {
        a0[j] = fmaf(f0, w[1 + j + k], a0[j]);
        a1[j] = fmaf(f1, w[1 + j + k], a1[j]);
      }
    }
    float e[4];
#pragma unroll
    for (int j = 0; j < 4; ++j) {
      const float th0 = 1.f - 2.f / (__expf(2.f * a0[j]) + 1.f);
      const float th1 = 1.f - 2.f / (__expf(2.f * a1[j]) + 1.f);
      e[j] = wev.x * th0 + wev.y * th1;
    }
#pragma unroll
    for (int m = 1; m < 64; m <<= 1) {
#pragma unroll
      for (int j = 0; j < 4; ++j) e[j] += __shfl_xor(e[j], m, 64);
    }
    if (lane == 0)
      *(float4*)&ws[WS_EN + b * TT + t0 + tq] = make_float4(e[0], e[1], e[2], e[3]);
    // online softmax update (all lanes hold e[0..3] after butterfly)
    float mq = fmaxf(fmaxf(e[0], e[1]), fmaxf(e[2], e[3]));
    float mn = fmaxf(om, mq);
    os = os * __expf(om - mn) + __expf(e[0] - mn) + __expf(e[1] - mn) +
         __expf(e[2] - mn) + __expf(e[3] - mn);
    om = mn;
  }

  __shared__ float sm[4], ss[4];
  if (lane == 0) { sm[wave] = om; ss[wave] = os; }
  __syncthreads();
  if (tid == 0) {
    const float mb = fmaxf(fmaxf(sm[0], sm[1]), fmaxf(sm[2], sm[3]));
    const float sb = ss[0] * __expf(sm[0] - mb) + ss[1] * __expf(sm[1] - mb) +
                     ss[2] * __expf(sm[2] - mb) + ss[3] * __expf(sm[3] - mb);
    float* st = ws + WS_ST + (b * 16 + chunk) * 2;
    st[0] = mb;
    st[1] = sb;
  }
}

// ---------------------------------------------------------------------------
// k3: per (b,ts): combine chunk stats -> (m_b, 1/S); compute + write the
// normalized weights for this 128-t slice; accumulate context partial;
// last block per b reduces 16 partials -> ctx (fixed order, deterministic).
// ---------------------------------------------------------------------------
__global__ __launch_bounds__(256) void k3_ctx(const float* __restrict__ enc,
                                              float* __restrict__ ws,
                                              float* __restrict__ wts,
                                              float* __restrict__ ctx) {
  const int ts = blockIdx.x;  // 0..15
  const int b = blockIdx.y;
  const int tid = threadIdx.x;
  const int t0 = ts * 128;

  // combine chunk stats (redundant per block; 32 floats from L2)
  const float* st = ws + WS_ST + b * 32;
  float mb = -3.4e38f;
#pragma unroll
  for (int c = 0; c < 16; ++c) mb = fmaxf(mb, st[2 * c]);
  float S = 0.f;
#pragma unroll
  for (int c = 0; c < 16; ++c) S += st[2 * c + 1] * __expf(st[2 * c] - mb);
  const float inv = 1.f / S;

  __shared__ float w_s[128];
  __shared__ __align__(16) float4 acc_s[128];
  if (tid < 128) {
    const float e = ws[WS_EN + b * TT + t0 + tid];
    const float w = __expf(e - mb) * inv;
    w_s[tid] = w;
    wts[b * TT + t0 + tid] = w;
  }
  __syncthreads();

  const float4* enc4 = (const float4*)(enc + (size_t)b * TT * EE);
  const int tp = tid >> 7;   // 0/1: row parity
  const int e4 = tid & 127;  // float4 column
  float4 acc0 = {0.f, 0.f, 0.f, 0.f}, acc1 = {0.f, 0.f, 0.f, 0.f};
#pragma unroll 8
  for (int i = 0; i < 64; ++i) {
    const int t = tp + 2 * i;
    const float w = w_s[t];
    const float4 v = enc4[(size_t)(t0 + t) * 128 + e4];
    if (i & 1) {
      acc1.x = fmaf(w, v.x, acc1.x); acc1.y = fmaf(w, v.y, acc1.y);
      acc1.z = fmaf(w, v.z, acc1.z); acc1.w = fmaf(w, v.w, acc1.w);
    } else {
      acc0.x = fmaf(w, v.x, acc0.x); acc0.y = fmaf(w, v.y, acc0.y);
      acc0.z = fmaf(w, v.z, acc0.z); acc0.w = fmaf(w, v.w, acc0.w);
    }
  }
  acc0.x += acc1.x; acc0.y += acc1.y; acc0.z += acc1.z; acc0.w += acc1.w;
  if (tp == 1) acc_s[e4] = acc0;
  __syncthreads();
  if (tp == 0) {
    const float4 o = acc_s[e4];
    acc0.x += o.x; acc0.y += o.y; acc0.z += o.z; acc0.w += o.w;
    ((float4*)(ws + WS_PART))[(size_t)(b * 16 + ts) * 128 + e4] = acc0;
  }

  // release partials, count blocks, last block reduces
  __threadfence();
  __syncthreads();
  __shared__ int isLast;
  if (tid == 0) {
    const int c = atomicAdd((int*)(ws + WS_CNT) + b, 1);
    isLast = (c == 15);
  }
  __syncthreads();
  if (isLast) {
    __threadfence();  // acquire: invalidate stale cached partials
    if (tid < 128) {
      const float4* p4 = (const float4*)(ws + WS_PART) + (size_t)b * 16 * 128 + tid;
      float4 s = {0.f, 0.f, 0.f, 0.f};
#pragma unroll
      for (int c = 0; c < 16; ++c) {
        const float4 v = p4[c * 128];
        s.x += v.x; s.y += v.y; s.z += v.z; s.w += v.w;
      }
      ((float4*)ctx)[b * 128 + tid] = s;
    }
  }
}

// ---------------------------------------------------------------------------
extern "C" void kernel_launch(void* const* d_in, const int* in_sizes, int n_in,
                              void* d_out, int out_size, void* d_ws, size_t ws_size,
                              hipStream_t stream) {
  const float* enc  = (const float*)d_in[0];  // [B,T,E]
  const float* pe   = (const float*)d_in[1];  // [B,T,H]
  const float* lstm = (const float*)d_in[2];  // [B,1,DL]
  const float* awc  = (const float*)d_in[3];  // [B,T]
  const float* Wl   = (const float*)d_in[4];  // [H,DL]
  const float* cw   = (const float*)d_in[5];  // [CC,1,K]
  const float* Wloc = (const float*)d_in[6];  // [H,CC]
  const float* We   = (const float*)d_in[7];  // [1,H]

  float* out = (float*)d_out;
  float* ctx = out;            // [B,E]
  float* wts = out + BB * EE;  // [B,T]
  float* ws = (float*)d_ws;

  k0_prep<<<2049, 256, 0, stream>>>(lstm, Wl, cw, Wloc, ws);
  k1_energies<<<dim3(16, BB), 256, 0, stream>>>(pe, awc, We, ws);
  k3_ctx<<<dim3(16, BB), 256, 0, stream>>>(enc, ws, wts, ctx);
}

// Round 4
// 98.806 us; speedup vs baseline: 3.1591x; 3.1591x over previous
//
#include <hip/hip_runtime.h>
#include <math.h>

// Tacotron2 location-sensitive attention, fp32.
// B=64 T=2048 E=512 H=128 DL=1024 CC=32 K=31
// out = [context (B*E=32768), weights (B*T=131072)] fp32, concatenated.
// 4 dispatches: k0 (prep), k1 (energies + chunk softmax stats),
// k3_ctx (weights + context partials), k3_reduce (ctx).
// NO device-scope fences/atomics: R3 showed __threadfence() per block
// (L2 writeback on non-coherent XCD L2s) costs 7x. Dispatch boundary is
// the cheap global barrier.

#define BB 64
#define TT 2048
#define EE 512
#define HH 128
#define DLL 1024
#define CCC 32
#define KK 31

// ws layout (in floats)
#define WS_FW   0        // fw[128][32]                 -> 4096
#define WS_PL   4096     // pl[64][128]                 -> 8192
#define WS_EN   12288    // energies[64][2048]          -> 131072
#define WS_ST   143360   // stats[64][16][2] (m,s)      -> 2048
#define WS_PART 145472   // partials[64][32][512]       -> 1048576

// ---------------------------------------------------------------------------
// k0: blocks 0..2047: one wave per (b,h) dot  pl[b][h] = lstm[b]·W_lstm[h]
//     block 2048: fw[h][k] = sum_c W_loc[h][c]*conv_w[c][k]
// ---------------------------------------------------------------------------
__global__ __launch_bounds__(256) void k0_prep(const float* __restrict__ lstm,
                                               const float* __restrict__ Wl,
                                               const float* __restrict__ cw,
                                               const float* __restrict__ Wloc,
                                               float* __restrict__ ws) {
  const int blk = blockIdx.x;
  const int tid = threadIdx.x;
  if (blk < 2048) {
    const int wave = tid >> 6, lane = tid & 63;
    const int wg = blk * 4 + wave;      // 0..8191
    const int b = wg >> 7, h = wg & 127;
    const float4* wr = (const float4*)(Wl + (size_t)h * DLL);
    const float4* lr = (const float4*)(lstm + (size_t)b * DLL);
    float s = 0.f;
#pragma unroll
    for (int m = 0; m < 4; ++m) {
      float4 a = wr[m * 64 + lane];
      float4 c = lr[m * 64 + lane];
      s += a.x * c.x + a.y * c.y + a.z * c.z + a.w * c.w;
    }
#pragma unroll
    for (int m = 1; m < 64; m <<= 1) s += __shfl_xor(s, m, 64);
    if (lane == 0) ws[WS_PL + b * HH + h] = s;
  } else {
    __shared__ __align__(16) float wl_s[HH * CCC];  // 4096
    __shared__ __align__(16) float cw_s[CCC * KK];  // 992
#pragma unroll
    for (int m = 0; m < 4; ++m)
      ((float4*)wl_s)[tid + 256 * m] = ((const float4*)Wloc)[tid + 256 * m];
    if (tid < 248) ((float4*)cw_s)[tid] = ((const float4*)cw)[tid];
    __syncthreads();
    const int h = tid >> 1;
    const int kbase = (tid & 1) * 16;
    const int kn = (tid & 1) ? 15 : 16;
    for (int kk = 0; kk < kn; ++kk) {
      const int k = kbase + kk;
      float s = 0.f;
#pragma unroll
      for (int c = 0; c < CCC; ++c) s += wl_s[h * CCC + c] * cw_s[c * KK + k];
      ws[WS_FW + h * 32 + k] = s;
    }
    if (tid & 1) ws[WS_FW + h * 32 + 31] = 0.f;  // pad
  }
}

// ---------------------------------------------------------------------------
// k1: energies[b][t] = sum_h We[h] * tanh(pl[b][h] + pe[b][t][h] + conv_h)
//     conv_h = sum_k fw[h][k] * aw[b][t+k-15] (zero pad)
// Writes raw energies to ws + per-chunk online softmax stats (m_c, s_c).
// t-chunk 128 per block, grid (16,64). One wave per 4 consecutive t;
// lane owns h in {2*lane, 2*lane+1}.
// ---------------------------------------------------------------------------
__global__ __launch_bounds__(256) void k1_energies(const float* __restrict__ pe,
                                                   const float* __restrict__ aw,
                                                   const float* __restrict__ We,
                                                   float* __restrict__ ws) {
  const int b = blockIdx.y;
  const int chunk = blockIdx.x;
  const int t0 = chunk * 128;
  const int tid = threadIdx.x;
  const int wave = tid >> 6, lane = tid & 63;

  __shared__ __align__(16) float aw_s[160];  // aw[t0-16 .. t0+143], zero-pad
  if (tid < 160) {
    const int tg = t0 - 16 + tid;
    aw_s[tid] = (tg >= 0 && tg < TT) ? aw[b * TT + tg] : 0.f;
  }

  const int h0 = 2 * lane;
  float fw0[32], fw1[32];
  {
    const float4* f4 = (const float4*)(ws + WS_FW);
#pragma unroll
    for (int m = 0; m < 8; ++m) {
      float4 a = f4[h0 * 8 + m];
      fw0[4 * m + 0] = a.x; fw0[4 * m + 1] = a.y;
      fw0[4 * m + 2] = a.z; fw0[4 * m + 3] = a.w;
      float4 c = f4[h0 * 8 + 8 + m];
      fw1[4 * m + 0] = c.x; fw1[4 * m + 1] = c.y;
      fw1[4 * m + 2] = c.z; fw1[4 * m + 3] = c.w;
    }
  }
  const float2 plv = ((const float2*)(ws + WS_PL + b * HH))[lane];
  const float2 wev = ((const float2*)We)[lane];
  const float2* pe2 = (const float2*)(pe + (size_t)b * TT * HH);

  __syncthreads();

  float om = -3.4e38f, os = 0.f;  // online softmax (per-wave; lanes identical)

  for (int p = 0; p < 8; ++p) {
    const int tq = wave * 32 + p * 4;  // local quad start
    float2 pv[4];
#pragma unroll
    for (int j = 0; j < 4; ++j)
      pv[j] = pe2[(size_t)(t0 + tq + j) * 64 + lane];

    float w[36];
    const float4* a4 = (const float4*)&aw_s[tq];
#pragma unroll
    for (int m = 0; m < 9; ++m) {
      float4 v = a4[m];
      w[4 * m + 0] = v.x; w[4 * m + 1] = v.y;
      w[4 * m + 2] = v.z; w[4 * m + 3] = v.w;
    }

    float a0[4], a1[4];
#pragma unroll
    for (int j = 0; j < 4; ++j) {
      a0[j] = plv.x + pv[j].x;
      a1[j] = plv.y + pv[j].y;
    }
#pragma unroll
    for (int k = 0; k < 31; ++k) {
      const float f0 = fw0[k], f1 = fw1[k];
#pragma unroll
      for (int j = 0; j < 4; ++j) {
        a0[j] = fmaf(f0, w[1 + j + k], a0[j]);
        a1[j] = fmaf(f1, w[1 + j + k], a1[j]);
      }
    }
    float e[4];
#pragma unroll
    for (int j = 0; j < 4; ++j) {
      const float th0 = 1.f - 2.f / (__expf(2.f * a0[j]) + 1.f);
      const float th1 = 1.f - 2.f / (__expf(2.f * a1[j]) + 1.f);
      e[j] = wev.x * th0 + wev.y * th1;
    }
#pragma unroll
    for (int m = 1; m < 64; m <<= 1) {
#pragma unroll
      for (int j = 0; j < 4; ++j) e[j] += __shfl_xor(e[j], m, 64);
    }
    if (lane == 0)
      *(float4*)&ws[WS_EN + b * TT + t0 + tq] = make_float4(e[0], e[1], e[2], e[3]);
    // online softmax update (all lanes hold e[0..3] after butterfly)
    float mq = fmaxf(fmaxf(e[0], e[1]), fmaxf(e[2], e[3]));
    float mn = fmaxf(om, mq);
    os = os * __expf(om - mn) + __expf(e[0] - mn) + __expf(e[1] - mn) +
         __expf(e[2] - mn) + __expf(e[3] - mn);
    om = mn;
  }

  __shared__ float sm[4], ss[4];
  if (lane == 0) { sm[wave] = om; ss[wave] = os; }
  __syncthreads();
  if (tid == 0) {
    const float mb = fmaxf(fmaxf(sm[0], sm[1]), fmaxf(sm[2], sm[3]));
    const float sb = ss[0] * __expf(sm[0] - mb) + ss[1] * __expf(sm[1] - mb) +
                     ss[2] * __expf(sm[2] - mb) + ss[3] * __expf(sm[3] - mb);
    float* st = ws + WS_ST + (b * 16 + chunk) * 2;
    st[0] = mb;
    st[1] = sb;
  }
}

// ---------------------------------------------------------------------------
// k3_ctx: per (b,ts of 64 t): combine chunk stats -> (m_b, 1/S); compute +
// write normalized weights for this slice; stream enc, write ctx partial.
// grid (32,64) = 2048 blocks. No fences, no atomics.
// ---------------------------------------------------------------------------
__global__ __launch_bounds__(256) void k3_ctx(const float* __restrict__ enc,
                                              const float* __restrict__ ws,
                                              float* __restrict__ wts,
                                              float* __restrict__ part) {
  const int ts = blockIdx.x;  // 0..31
  const int b = blockIdx.y;
  const int tid = threadIdx.x;
  const int t0 = ts * 64;

  // combine chunk stats (redundant per block; 32 floats from L2)
  const float* st = ws + WS_ST + b * 32;
  float mb = -3.4e38f;
#pragma unroll
  for (int c = 0; c < 16; ++c) mb = fmaxf(mb, st[2 * c]);
  float S = 0.f;
#pragma unroll
  for (int c = 0; c < 16; ++c) S += st[2 * c + 1] * __expf(st[2 * c] - mb);
  const float inv = 1.f / S;

  __shared__ float w_s[64];
  __shared__ __align__(16) float4 acc_s[128];
  if (tid < 64) {
    const float e = ws[WS_EN + b * TT + t0 + tid];
    const float w = __expf(e - mb) * inv;
    w_s[tid] = w;
    wts[b * TT + t0 + tid] = w;
  }
  __syncthreads();

  const float4* enc4 = (const float4*)(enc + (size_t)b * TT * EE);
  const int tp = tid >> 7;   // 0/1: row parity
  const int e4 = tid & 127;  // float4 column
  float4 acc0 = {0.f, 0.f, 0.f, 0.f}, acc1 = {0.f, 0.f, 0.f, 0.f};
#pragma unroll 8
  for (int i = 0; i < 32; ++i) {
    const int t = tp + 2 * i;
    const float w = w_s[t];
    const float4 v = enc4[(size_t)(t0 + t) * 128 + e4];
    if (i & 1) {
      acc1.x = fmaf(w, v.x, acc1.x); acc1.y = fmaf(w, v.y, acc1.y);
      acc1.z = fmaf(w, v.z, acc1.z); acc1.w = fmaf(w, v.w, acc1.w);
    } else {
      acc0.x = fmaf(w, v.x, acc0.x); acc0.y = fmaf(w, v.y, acc0.y);
      acc0.z = fmaf(w, v.z, acc0.z); acc0.w = fmaf(w, v.w, acc0.w);
    }
  }
  acc0.x += acc1.x; acc0.y += acc1.y; acc0.z += acc1.z; acc0.w += acc1.w;
  if (tp == 1) acc_s[e4] = acc0;
  __syncthreads();
  if (tp == 0) {
    const float4 o = acc_s[e4];
    acc0.x += o.x; acc0.y += o.y; acc0.z += o.z; acc0.w += o.w;
    ((float4*)part)[(size_t)(b * 32 + ts) * 128 + e4] = acc0;
  }
}

// ---------------------------------------------------------------------------
// k3_reduce: ctx[b][e] = sum_ts part[b][ts][e], fixed order. 64 blocks.
// ---------------------------------------------------------------------------
__global__ __launch_bounds__(256) void k3_reduce(const float* __restrict__ part,
                                                 float* __restrict__ ctx) {
  const int b = blockIdx.x;
  const int e2 = threadIdx.x;  // float2 column 0..255
  const float2* p2 = (const float2*)part + (size_t)b * 32 * 256 + e2;
  float2 s = {0.f, 0.f};
#pragma unroll
  for (int ts = 0; ts < 32; ++ts) {
    const float2 v = p2[ts * 256];
    s.x += v.x;
    s.y += v.y;
  }
  ((float2*)ctx)[b * 256 + e2] = s;
}

// ---------------------------------------------------------------------------
extern "C" void kernel_launch(void* const* d_in, const int* in_sizes, int n_in,
                              void* d_out, int out_size, void* d_ws, size_t ws_size,
                              hipStream_t stream) {
  const float* enc  = (const float*)d_in[0];  // [B,T,E]
  const float* pe   = (const float*)d_in[1];  // [B,T,H]
  const float* lstm = (const float*)d_in[2];  // [B,1,DL]
  const float* awc  = (const float*)d_in[3];  // [B,T]
  const float* Wl   = (const float*)d_in[4];  // [H,DL]
  const float* cw   = (const float*)d_in[5];  // [CC,1,K]
  const float* Wloc = (const float*)d_in[6];  // [H,CC]
  const float* We   = (const float*)d_in[7];  // [1,H]

  float* out = (float*)d_out;
  float* ctx = out;            // [B,E]
  float* wts = out + BB * EE;  // [B,T]
  float* ws = (float*)d_ws;

  k0_prep<<<2049, 256, 0, stream>>>(lstm, Wl, cw, Wloc, ws);
  k1_energies<<<dim3(16, BB), 256, 0, stream>>>(pe, awc, We, ws);
  k3_ctx<<<dim3(32, BB), 256, 0, stream>>>(enc, ws, wts, ws + WS_PART);
  k3_reduce<<<BB, 256, 0, stream>>>(ws + WS_PART, ctx);
}